// Round 5
// baseline (196.255 us; speedup 1.0000x reference)
//
#include <hip/hip_runtime.h>

typedef __attribute__((ext_vector_type(8))) short short8;
typedef __attribute__((ext_vector_type(4))) float f32x4;
typedef __attribute__((ext_vector_type(16))) float f32x16;
typedef __attribute__((ext_vector_type(4))) unsigned short ushort4v;
typedef __attribute__((ext_vector_type(4))) unsigned int u32x4;
typedef unsigned short u16;
typedef unsigned int u32;

#define NN 1024
#define DD 512
#define DH 64
#define EXP2C 0.18033688f   /* 0.125 * log2(e) */

// ---------- helpers ----------

__device__ __forceinline__ u16 f2bf(float f) {
    unsigned u = __float_as_uint(f);
    u += 0x7fffu + ((u >> 16) & 1u);   // RNE
    return (u16)(u >> 16);
}

__device__ __forceinline__ short8 lds_ld128(const char* base, int row, int colbyte) {
    int off = (row * 128 + colbyte) ^ ((row & 7) << 4);
    return *(const short8*)(base + off);
}

__device__ __forceinline__ void stage128x64(const u16* g, int ldRow, char* lds,
                                            int wid, int lane) {
#pragma unroll
    for (int r = 0; r < 4; ++r) {
        int cidx = (r * 4 + wid) * 64 + lane;
        int row  = cidx >> 3;
        int ch   = (cidx & 7) ^ (row & 7);
        const char* src = (const char*)(g + row * ldRow) + ch * 16;
        __builtin_amdgcn_global_load_lds(
            (const __attribute__((address_space(1))) unsigned int*)src,
            (__attribute__((address_space(3))) unsigned int*)(lds + (r * 4 + wid) * 1024),
            16, 0, 0);
    }
}

// ---- fold-2 tile (32 rows x 128B): phys = line*256 + ((sub<<3 | (slot8^(line&7)))<<4)+lo
// line=jr>>1, sub=jr&1, slot8=db>>4.  Read (row=il, db=c0*16): 2-way bank alias.
__device__ __forceinline__ void stageF2(const u16* g /* row0, stride DD elems */,
                                        char* lds, int lane) {
#pragma unroll
    for (int r = 0; r < 4; ++r) {
        int c = r * 64 + lane;
        int line = c >> 4, s = c & 15;
        int jr = line * 2 + (s >> 3);
        int slot8 = (s & 7) ^ (line & 7);
        const char* src = (const char*)(g + (size_t)jr * DD) + slot8 * 16;
        __builtin_amdgcn_global_load_lds(
            (const __attribute__((address_space(1))) unsigned int*)src,
            (__attribute__((address_space(3))) unsigned int*)(lds + r * 1024),
            16, 0, 0);
    }
}
__device__ __forceinline__ short8 ldF2(const char* tile, int il, int hh, int t) {
    int c0 = t * 2 + hh;
    int addr = ((il >> 1) << 8) + ((il & 1) << 7) + (((c0 ^ ((il >> 1) & 7))) << 4);
    return *(const short8*)(tile + addr);
}

// ---- fold-4 tile (64 rows x 64B): phys = line*256 + ((slot16 ^ (line&7))<<4)+lo
// line=r>>2, slot16=(r&3)*4 + db>>4.
__device__ __forceinline__ void stageF4(const u16* g /* row0, stride 8192 elems */,
                                        char* lds, int lane) {
#pragma unroll
    for (int r = 0; r < 4; ++r) {
        int c = r * 64 + lane;
        int line = c >> 4, s = c & 15;
        int s16 = s ^ (line & 7);
        int rr = line * 4 + (s16 >> 2);
        int slot4 = s16 & 3;
        const char* src = (const char*)(g + (size_t)rr * 8192) + slot4 * 16;
        __builtin_amdgcn_global_load_lds(
            (const __attribute__((address_space(1))) unsigned int*)src,
            (__attribute__((address_space(3))) unsigned int*)(lds + r * 1024),
            16, 0, 0);
    }
}
__device__ __forceinline__ short8 ldF4(const char* tile, int il, int hh, int m, int tc) {
    int c0 = tc * 2 + hh;
    int line = m * 8 + (il >> 2);
    int s16 = (((il & 3) << 2) + c0) ^ ((il >> 2) & 7);
    return *(const short8*)(tile + line * 256 + (s16 << 4));
}

// ---------- fused fp32 -> bf16 convert ----------
__global__ void f2bf_all(const float* __restrict__ x, const float* __restrict__ ctx,
                         const float* __restrict__ Wq, const float* __restrict__ Wk,
                         const float* __restrict__ Wv, const float* __restrict__ Wo,
                         u16* __restrict__ xb, u16* __restrict__ cb,
                         u16* __restrict__ wb) {
    int i = blockIdx.x * blockDim.x + threadIdx.x;   // float4 index, 2359296 total
    const float* src;
    u16* dst;
    int off;
    if (i < 1048576)      { src = x;   dst = xb; off = i; }
    else if (i < 2097152) { src = ctx; dst = cb; off = i - 1048576; }
    else {
        int wi = i - 2097152;
        int which = wi >> 16;
        off = wi & 65535;
        dst = wb + (size_t)which * 262144;
        src = (which == 0) ? Wq : (which == 1) ? Wk : (which == 2) ? Wv : Wo;
    }
    float4 v = ((const float4*)src)[off];
    ushort4v o;
    o.x = f2bf(v.x); o.y = f2bf(v.y); o.z = f2bf(v.z); o.w = f2bf(v.w);
    *(ushort4v*)(dst + (size_t)off * 4) = o;
}

// ---------- fused QKV projection GEMMs: z selects (A,B,Out,layout) ----------
__global__ __launch_bounds__(256, 2) void gemm_qkv(
    const u16* __restrict__ xb, const u16* __restrict__ cb, const u16* __restrict__ wb,
    u16* __restrict__ qb, u16* __restrict__ kb, u16* __restrict__ vT)
{
    __shared__ char As[16384];
    __shared__ char Bs[16384];
    const int z = blockIdx.z;
    const u16* A = (z == 0) ? xb : cb;
    const u16* B = wb + (size_t)z * 262144;
    const int lane = threadIdx.x & 63;
    const int wid  = threadIdx.x >> 6;
    const int wr = wid >> 1, wc = wid & 1;
    const int n = blockIdx.x + 4 * blockIdx.y;
    const int L = (n & 7) * 32 + (n >> 3);
    const int rowBase = (L >> 2) * 128;
    const int colBase = (L & 3) * 128;

    f32x4 acc[4][4] = {};
    for (int kt = 0; kt < 8; ++kt) {
        __syncthreads();
        stage128x64(A + (size_t)rowBase * DD + kt * 64, DD, As, wid, lane);
        stage128x64(B + (size_t)colBase * DD + kt * 64, DD, Bs, wid, lane);
        __syncthreads();
#pragma unroll
        for (int kk = 0; kk < 2; ++kk) {
            const int cbb = kk * 64 + (lane >> 4) * 16;
            short8 af[4], bf[4];
#pragma unroll
            for (int m = 0; m < 4; ++m) af[m] = lds_ld128(As, wr * 64 + m * 16 + (lane & 15), cbb);
#pragma unroll
            for (int q = 0; q < 4; ++q) bf[q] = lds_ld128(Bs, wc * 64 + q * 16 + (lane & 15), cbb);
#pragma unroll
            for (int m = 0; m < 4; ++m) {
#pragma unroll
                for (int q = 0; q < 4; ++q)
                    acc[m][q] = __builtin_amdgcn_mfma_f32_16x16x32_bf16(af[m], bf[q], acc[m][q], 0, 0, 0);
            }
        }
    }
#pragma unroll
    for (int m = 0; m < 4; ++m) {
#pragma unroll
        for (int q = 0; q < 4; ++q) {
            const int r0 = rowBase + wr * 64 + m * 16 + ((lane >> 4) << 2);
            const int c  = colBase + wc * 64 + q * 16 + (lane & 15);
            if (z < 2) {
                u16* O = z ? kb : qb;
#pragma unroll
                for (int g = 0; g < 4; ++g) O[(size_t)(r0 + g) * DD + c] = f2bf(acc[m][q][g]);
            } else {
                ushort4v pk;
#pragma unroll
                for (int g = 0; g < 4; ++g) pk[g] = f2bf(acc[m][q][g]);
                *(ushort4v*)(vT + (size_t)c * 8192 + r0) = pk;
            }
        }
    }
}

// ---------- final GEMM: fp32 out + bias ----------
__global__ __launch_bounds__(256, 2) void gemm_out(
    const u16* __restrict__ A, const u16* __restrict__ B,
    float* __restrict__ Out, const float* __restrict__ bias)
{
    __shared__ char As[16384];
    __shared__ char Bs[16384];
    const int lane = threadIdx.x & 63;
    const int wid  = threadIdx.x >> 6;
    const int wr = wid >> 1, wc = wid & 1;
    const int n = blockIdx.x + 4 * blockIdx.y;
    const int L = (n & 7) * 32 + (n >> 3);
    const int rowBase = (L >> 2) * 128;
    const int colBase = (L & 3) * 128;

    f32x4 acc[4][4] = {};
    for (int kt = 0; kt < 8; ++kt) {
        __syncthreads();
        stage128x64(A + (size_t)rowBase * DD + kt * 64, DD, As, wid, lane);
        stage128x64(B + (size_t)colBase * DD + kt * 64, DD, Bs, wid, lane);
        __syncthreads();
#pragma unroll
        for (int kk = 0; kk < 2; ++kk) {
            const int cbb = kk * 64 + (lane >> 4) * 16;
            short8 af[4], bf[4];
#pragma unroll
            for (int m = 0; m < 4; ++m) af[m] = lds_ld128(As, wr * 64 + m * 16 + (lane & 15), cbb);
#pragma unroll
            for (int q = 0; q < 4; ++q) bf[q] = lds_ld128(Bs, wc * 64 + q * 16 + (lane & 15), cbb);
#pragma unroll
            for (int m = 0; m < 4; ++m) {
#pragma unroll
                for (int q = 0; q < 4; ++q)
                    acc[m][q] = __builtin_amdgcn_mfma_f32_16x16x32_bf16(af[m], bf[q], acc[m][q], 0, 0, 0);
            }
        }
    }
#pragma unroll
    for (int m = 0; m < 4; ++m) {
#pragma unroll
        for (int q = 0; q < 4; ++q) {
            const int r0 = rowBase + wr * 64 + m * 16 + ((lane >> 4) << 2);
            const int c  = colBase + wc * 64 + q * 16 + (lane & 15);
            const float bb = bias[c];
#pragma unroll
            for (int g = 0; g < 4; ++g) Out[(size_t)(r0 + g) * DD + c] = acc[m][q][g] + bb;
        }
    }
}

// ---------- pass 1: inv column-sum of exp(sim) ----------
// 512 thr = 8 waves: jbp = wid&1 (j band), iq = wid>>1 (i quarter). Q tiles via LDS.
__global__ __launch_bounds__(512, 4) void colsum_k(
    const u16* __restrict__ qb, const u16* __restrict__ kb, float* __restrict__ invcol)
{
    alignas(16) __shared__ char smem[16384];
    __shared__ float csum[64];
    const int lane = threadIdx.x & 63;
    const int wid  = threadIdx.x >> 6;
    const int il = lane & 31, hh = lane >> 5;
    const int n = blockIdx.x + 16 * blockIdx.y;
    const int L = (n & 7) * 128 + (n >> 3);
    const int xt = L & 15;
    const int bh = L >> 4;
    const int b = bh >> 3, h = bh & 7;
    const int jbp = wid & 1;
    const int iq  = wid >> 1;
    const int jbase = (xt * 2 + jbp) * 32;
    char* Qt = smem + iq * 4096;

    if (threadIdx.x < 64) csum[threadIdx.x] = 0.0f;

    const u16* kRow = kb + (size_t)(b * NN + jbase + il) * DD + h * DH + hh * 8;
    short8 kf[4];
#pragma unroll
    for (int t = 0; t < 4; ++t) kf[t] = *(const short8*)(kRow + t * 16);

    if (jbp == 0)
        stageF2(qb + (size_t)(b * NN + iq * 256) * DD + h * DH, Qt, lane);

    float cp[16] = {};
    for (int u = 0; u < 8; ++u) {
        __syncthreads();                       // stage(u) complete
        short8 qf[4];
#pragma unroll
        for (int t = 0; t < 4; ++t) qf[t] = ldF2(Qt, il, hh, t);
        __syncthreads();                       // reads drained
        if (u < 7 && jbp == 0)
            stageF2(qb + (size_t)(b * NN + iq * 256 + (u + 1) * 32) * DD + h * DH, Qt, lane);
        f32x16 sa = {};
#pragma unroll
        for (int t = 0; t < 4; ++t)
            sa = __builtin_amdgcn_mfma_f32_32x32x16_bf16(kf[t], qf[t], sa, 0, 0, 0);
#pragma unroll
        for (int r = 0; r < 16; ++r) cp[r] += exp2f(sa[r] * EXP2C);
    }
#pragma unroll
    for (int r = 0; r < 16; ++r) {
        cp[r] += __shfl_xor(cp[r], 1);
        cp[r] += __shfl_xor(cp[r], 2);
        cp[r] += __shfl_xor(cp[r], 4);
        cp[r] += __shfl_xor(cp[r], 8);
        cp[r] += __shfl_xor(cp[r], 16);
    }
    if (il == 0) {
#pragma unroll
        for (int r = 0; r < 16; ++r)
            atomicAdd(&csum[jbp * 32 + (r & 3) + 8 * (r >> 2) + 4 * hh], cp[r]);
    }
    __syncthreads();
    if (threadIdx.x < 64)
        invcol[(size_t)bh * NN + xt * 64 + threadIdx.x] = 1.0f / csum[threadIdx.x];
}

// ---------- pass 2: out^T = V^T @ P^T, P = exp(sim)*invcol ----------
// 512 thr = 8 waves: ibp = wid&1 (i band), jq = wid>>1 (j quarter). K/V via LDS.
__global__ __launch_bounds__(512, 4) void attn_k(
    const u16* __restrict__ qb, const u16* __restrict__ kb, const u16* __restrict__ vT,
    const float* __restrict__ invcol, u16* __restrict__ ob)
{
    alignas(16) __shared__ char smem[33792];
    const int lane = threadIdx.x & 63;
    const int wid  = threadIdx.x >> 6;
    const int il = lane & 31, hh = lane >> 5;
    const int n = blockIdx.x + 16 * blockIdx.y;
    const int L = (n & 7) * 128 + (n >> 3);
    const int xt = L & 15;
    const int bh = L >> 4;
    const int b = bh >> 3, h = bh & 7;
    const int ibp = wid & 1;
    const int jq  = wid >> 1;
    const int ibase = (xt * 2 + ibp) * 32;
    char* Kt = smem + jq * 8192;
    char* Vt = smem + jq * 8192 + 4096;
    float* cO = (float*)smem;                 // [ibp][slot][32][64] (reuse after loop)
    float* cR = (float*)(smem + 32768);       // [ibp][slot][64]

    const u16* qRow = qb + (size_t)(b * NN + ibase + il) * DD + h * DH + hh * 8;
    short8 qf[4];
#pragma unroll
    for (int t = 0; t < 4; ++t) qf[t] = *(const short8*)(qRow + t * 16);
    const float* icbase = invcol + (size_t)bh * NN + 4 * hh;

    if (ibp == 0) stageF2(kb + (size_t)(b * NN + jq * 256) * DD + h * DH, Kt, lane);
    else          stageF4(vT + (size_t)h * DH * 8192 + b * NN + jq * 256, Vt, lane);

    f32x16 oacc[2] = {};
    float rs = 0.0f;

    for (int u = 0; u < 8; ++u) {
        const int jb = jq * 256 + u * 32;
        __syncthreads();                       // stage(u) complete
        short8 kf[4], vf[2][2];
#pragma unroll
        for (int t = 0; t < 4; ++t) kf[t] = ldF2(Kt, il, hh, t);
#pragma unroll
        for (int m = 0; m < 2; ++m)
#pragma unroll
            for (int tc = 0; tc < 2; ++tc) vf[m][tc] = ldF4(Vt, il, hh, m, tc);
        __syncthreads();                       // reads drained
        if (u < 7) {
            if (ibp == 0) stageF2(kb + (size_t)(b * NN + jb + 32) * DD + h * DH, Kt, lane);
            else          stageF4(vT + (size_t)h * DH * 8192 + b * NN + jb + 32, Vt, lane);
        }
        f32x16 sa = {};
#pragma unroll
        for (int t = 0; t < 4; ++t)
            sa = __builtin_amdgcn_mfma_f32_32x32x16_bf16(kf[t], qf[t], sa, 0, 0, 0);
        u32 pk[4][2];
#pragma unroll
        for (int s = 0; s < 4; ++s) {
            const float4 ic = *(const float4*)(icbase + jb + 8 * s);
            const float p0 = exp2f(sa[4 * s + 0] * EXP2C) * ic.x;
            const float p1 = exp2f(sa[4 * s + 1] * EXP2C) * ic.y;
            const float p2 = exp2f(sa[4 * s + 2] * EXP2C) * ic.z;
            const float p3 = exp2f(sa[4 * s + 3] * EXP2C) * ic.w;
            rs += (p0 + p1) + (p2 + p3);
            pk[s][0] = (u32)f2bf(p0) | ((u32)f2bf(p1) << 16);
            pk[s][1] = (u32)f2bf(p2) | ((u32)f2bf(p3) << 16);
        }
#pragma unroll
        for (int tc = 0; tc < 2; ++tc) {
            const u32 snd0 = hh ? pk[2 * tc][0] : pk[2 * tc + 1][0];
            const u32 snd1 = hh ? pk[2 * tc][1] : pk[2 * tc + 1][1];
            const u32 rcv0 = (u32)__shfl_xor((int)snd0, 32);
            const u32 rcv1 = (u32)__shfl_xor((int)snd1, 32);
            u32x4 pw;
            pw.x = hh ? rcv0 : pk[2 * tc][0];
            pw.y = hh ? rcv1 : pk[2 * tc][1];
            pw.z = hh ? pk[2 * tc + 1][0] : rcv0;
            pw.w = hh ? pk[2 * tc + 1][1] : rcv1;
            const short8 pf = __builtin_bit_cast(short8, pw);
#pragma unroll
            for (int m = 0; m < 2; ++m)
                oacc[m] = __builtin_amdgcn_mfma_f32_32x32x16_bf16(vf[m][tc], pf, oacc[m], 0, 0, 0);
        }
    }

    rs += __shfl_xor(rs, 32);
    __syncthreads();                           // staging dead; smem becomes combine buf
    if (jq & 1) {
        const int slot = jq >> 1;
#pragma unroll
        for (int m = 0; m < 2; ++m)
#pragma unroll
            for (int r = 0; r < 16; ++r)
                cO[(((ibp * 2 + slot) * 32) + m * 16 + r) * 64 + lane] = oacc[m][r];
        cR[(ibp * 2 + slot) * 64 + lane] = rs;
    }
    __syncthreads();
    if ((jq & 1) == 0) {
        const int slot = jq >> 1;
#pragma unroll
        for (int m = 0; m < 2; ++m)
#pragma unroll
            for (int r = 0; r < 16; ++r)
                oacc[m][r] += cO[(((ibp * 2 + slot) * 32) + m * 16 + r) * 64 + lane];
        rs += cR[(ibp * 2 + slot) * 64 + lane];
    }
    if (jq == 2) {
#pragma unroll
        for (int m = 0; m < 2; ++m)
#pragma unroll
            for (int r = 0; r < 16; ++r)
                cO[(((ibp * 2 + 1) * 32) + m * 16 + r) * 64 + lane] = oacc[m][r];
        cR[(ibp * 2 + 1) * 64 + lane] = rs;
    }
    __syncthreads();
    if (jq == 0) {
#pragma unroll
        for (int m = 0; m < 2; ++m)
#pragma unroll
            for (int r = 0; r < 16; ++r)
                oacc[m][r] += cO[(((ibp * 2 + 1) * 32) + m * 16 + r) * 64 + lane];
        rs += cR[(ibp * 2 + 1) * 64 + lane];
        const float inv = 1.0f / (rs + 1e-7f);
        u16* oRow = ob + (size_t)(b * NN + ibase + il) * DD + h * DH;
#pragma unroll
        for (int m = 0; m < 2; ++m) {
#pragma unroll
            for (int s = 0; s < 4; ++s) {
                ushort4v st;
#pragma unroll
                for (int g = 0; g < 4; ++g) st[g] = f2bf(oacc[m][4 * s + g] * inv);
                *(ushort4v*)(oRow + m * 32 + 8 * s + 4 * hh) = st;
            }
        }
    }
}

// ---------- launcher ----------

extern "C" void kernel_launch(void* const* d_in, const int* in_sizes, int n_in,
                              void* d_out, int out_size, void* d_ws, size_t ws_size,
                              hipStream_t stream)
{
    (void)in_sizes; (void)n_in; (void)out_size; (void)ws_size;
    const float* x   = (const float*)d_in[0];
    const float* ctx = (const float*)d_in[1];
    const float* Wq  = (const float*)d_in[2];
    const float* Wk  = (const float*)d_in[3];
    const float* Wv  = (const float*)d_in[4];
    const float* Wo  = (const float*)d_in[5];
    const float* bo  = (const float*)d_in[6];
    float* out = (float*)d_out;

    char* w = (char*)d_ws;
    const size_t SZBIG = 8192ull * 512 * 2;            // 8 MiB bf16 buffer
    u16* xb  = (u16*)(w);
    u16* cb  = (u16*)(w + SZBIG);
    u16* qb  = (u16*)(w + 2 * SZBIG);
    u16* kb  = (u16*)(w + 3 * SZBIG);
    u16* vT  = (u16*)(w + 4 * SZBIG);                  // [512][8192]
    u16* wb  = (u16*)(w + 5 * SZBIG);                  // wq,wk,wv,wo contiguous
    u16* wob = wb + 3 * 262144;
    float* invcol = (float*)(w + 5 * SZBIG + 4 * 524288);
    u16* ob = xb;                                      // reuse (x dead after q GEMM)

    f2bf_all<<<9216, 256, 0, stream>>>(x, ctx, Wq, Wk, Wv, Wo, xb, cb, wb);

    gemm_qkv<<<dim3(4, 64, 3), 256, 0, stream>>>(xb, cb, wb, qb, kb, vT);

    colsum_k<<<dim3(16, 64), 512, 0, stream>>>(qb, kb, invcol);
    attn_k  <<<dim3(16, 64), 512, 0, stream>>>(qb, kb, vT, invcol, ob);

    gemm_out<<<dim3(4, 64), 256, 0, stream>>>(ob, wob, out, bo);
}

// Round 6
// 111.868 us; speedup vs baseline: 1.7543x; 1.7543x over previous
//
#include <hip/hip_runtime.h>

typedef __attribute__((ext_vector_type(8))) short short8;
typedef __attribute__((ext_vector_type(4))) float f32x4;
typedef __attribute__((ext_vector_type(16))) float f32x16;
typedef __attribute__((ext_vector_type(4))) unsigned short ushort4v;
typedef __attribute__((ext_vector_type(4))) unsigned int u32x4;
typedef unsigned short u16;
typedef unsigned int u32;

#define NN 1024
#define DD 512
#define DH 64
#define EXP2C 0.18033688f   /* 0.125 * log2(e) */

// ---------- helpers ----------

__device__ __forceinline__ u16 f2bf(float f) {
    unsigned u = __float_as_uint(f);
    u += 0x7fffu + ((u >> 16) & 1u);   // RNE
    return (u16)(u >> 16);
}

__device__ __forceinline__ void stage_gll(const char* src, char* dst) {
    __builtin_amdgcn_global_load_lds(
        (const __attribute__((address_space(1))) unsigned int*)src,
        (__attribute__((address_space(3))) unsigned int*)dst, 16, 0, 0);
}

__device__ __forceinline__ short8 lds_ld128(const char* base, int row, int colbyte) {
    int off = (row * 128 + colbyte) ^ ((row & 7) << 4);
    return *(const short8*)(base + off);
}

__device__ __forceinline__ void stage128x64(const u16* g, int ldRow, char* lds,
                                            int wid, int lane) {
#pragma unroll
    for (int r = 0; r < 4; ++r) {
        int cidx = (r * 4 + wid) * 64 + lane;
        int row  = cidx >> 3;
        int ch   = (cidx & 7) ^ (row & 7);
        const char* src = (const char*)(g + row * ldRow) + ch * 16;
        stage_gll(src, lds + (r * 4 + wid) * 1024);
    }
}

// fold-2 tile (32 rows x 128B, 4KB): phys chunk s (0..255): line=s>>4, s15=s&15,
// holds row line*2+(s15>>3), source chunk (s15&7)^(line&7).
__device__ __forceinline__ short8 ldF2(const char* tile, int il, int hh, int t) {
    int c0 = t * 2 + hh;
    int addr = ((il >> 1) << 8) + ((il & 1) << 7) + ((c0 ^ ((il >> 1) & 7)) << 4);
    return *(const short8*)(tile + addr);
}

// fold-4 tile (64 rows x 64B, 4KB): phys chunk s: line=s>>4, s16=(s&15)^(line&7),
// holds row line*4+(s16>>2), source chunk s16&3.
__device__ __forceinline__ short8 ldF4(const char* tile, int il, int hh, int m, int tc) {
    int c0 = tc * 2 + hh;
    int line = m * 8 + (il >> 2);
    int s16 = (((il & 3) << 2) + c0) ^ ((il >> 2) & 7);
    return *(const short8*)(tile + line * 256 + (s16 << 4));
}

// ---------- fused fp32 -> bf16 convert ----------
__global__ void f2bf_all(const float* __restrict__ x, const float* __restrict__ ctx,
                         const float* __restrict__ Wq, const float* __restrict__ Wk,
                         const float* __restrict__ Wv, const float* __restrict__ Wo,
                         u16* __restrict__ xb, u16* __restrict__ cb,
                         u16* __restrict__ wb) {
    int i = blockIdx.x * blockDim.x + threadIdx.x;   // float4 index, 2359296 total
    const float* src;
    u16* dst;
    int off;
    if (i < 1048576)      { src = x;   dst = xb; off = i; }
    else if (i < 2097152) { src = ctx; dst = cb; off = i - 1048576; }
    else {
        int wi = i - 2097152;
        int which = wi >> 16;
        off = wi & 65535;
        dst = wb + (size_t)which * 262144;
        src = (which == 0) ? Wq : (which == 1) ? Wk : (which == 2) ? Wv : Wo;
    }
    float4 v = ((const float4*)src)[off];
    ushort4v o;
    o.x = f2bf(v.x); o.y = f2bf(v.y); o.z = f2bf(v.z); o.w = f2bf(v.w);
    *(ushort4v*)(dst + (size_t)off * 4) = o;
}

// ---------- fused QKV projection GEMMs ----------
__global__ __launch_bounds__(256, 2) void gemm_qkv(
    const u16* __restrict__ xb, const u16* __restrict__ cb, const u16* __restrict__ wb,
    u16* __restrict__ qb, u16* __restrict__ kb, u16* __restrict__ vT)
{
    __shared__ char As[16384];
    __shared__ char Bs[16384];
    const int z = blockIdx.z;
    const u16* A = (z == 0) ? xb : cb;
    const u16* B = wb + (size_t)z * 262144;
    const int lane = threadIdx.x & 63;
    const int wid  = threadIdx.x >> 6;
    const int wr = wid >> 1, wc = wid & 1;
    const int n = blockIdx.x + 4 * blockIdx.y;
    const int L = (n & 7) * 32 + (n >> 3);
    const int rowBase = (L >> 2) * 128;
    const int colBase = (L & 3) * 128;

    f32x4 acc[4][4] = {};
    for (int kt = 0; kt < 8; ++kt) {
        __syncthreads();
        stage128x64(A + (size_t)rowBase * DD + kt * 64, DD, As, wid, lane);
        stage128x64(B + (size_t)colBase * DD + kt * 64, DD, Bs, wid, lane);
        __syncthreads();
#pragma unroll
        for (int kk = 0; kk < 2; ++kk) {
            const int cbb = kk * 64 + (lane >> 4) * 16;
            short8 af[4], bf[4];
#pragma unroll
            for (int m = 0; m < 4; ++m) af[m] = lds_ld128(As, wr * 64 + m * 16 + (lane & 15), cbb);
#pragma unroll
            for (int q = 0; q < 4; ++q) bf[q] = lds_ld128(Bs, wc * 64 + q * 16 + (lane & 15), cbb);
#pragma unroll
            for (int m = 0; m < 4; ++m) {
#pragma unroll
                for (int q = 0; q < 4; ++q)
                    acc[m][q] = __builtin_amdgcn_mfma_f32_16x16x32_bf16(af[m], bf[q], acc[m][q], 0, 0, 0);
            }
        }
    }
#pragma unroll
    for (int m = 0; m < 4; ++m) {
#pragma unroll
        for (int q = 0; q < 4; ++q) {
            const int r0 = rowBase + wr * 64 + m * 16 + ((lane >> 4) << 2);
            const int c  = colBase + wc * 64 + q * 16 + (lane & 15);
            if (z < 2) {
                u16* O = z ? kb : qb;
#pragma unroll
                for (int g = 0; g < 4; ++g) O[(size_t)(r0 + g) * DD + c] = f2bf(acc[m][q][g]);
            } else {
                ushort4v pk;
#pragma unroll
                for (int g = 0; g < 4; ++g) pk[g] = f2bf(acc[m][q][g]);
                *(ushort4v*)(vT + (size_t)c * 8192 + r0) = pk;
            }
        }
    }
}

// ---------- final GEMM: fp32 out + bias ----------
__global__ __launch_bounds__(256, 2) void gemm_out(
    const u16* __restrict__ A, const u16* __restrict__ B,
    float* __restrict__ Out, const float* __restrict__ bias)
{
    __shared__ char As[16384];
    __shared__ char Bs[16384];
    const int lane = threadIdx.x & 63;
    const int wid  = threadIdx.x >> 6;
    const int wr = wid >> 1, wc = wid & 1;
    const int n = blockIdx.x + 4 * blockIdx.y;
    const int L = (n & 7) * 32 + (n >> 3);
    const int rowBase = (L >> 2) * 128;
    const int colBase = (L & 3) * 128;

    f32x4 acc[4][4] = {};
    for (int kt = 0; kt < 8; ++kt) {
        __syncthreads();
        stage128x64(A + (size_t)rowBase * DD + kt * 64, DD, As, wid, lane);
        stage128x64(B + (size_t)colBase * DD + kt * 64, DD, Bs, wid, lane);
        __syncthreads();
#pragma unroll
        for (int kk = 0; kk < 2; ++kk) {
            const int cbb = kk * 64 + (lane >> 4) * 16;
            short8 af[4], bf[4];
#pragma unroll
            for (int m = 0; m < 4; ++m) af[m] = lds_ld128(As, wr * 64 + m * 16 + (lane & 15), cbb);
#pragma unroll
            for (int q = 0; q < 4; ++q) bf[q] = lds_ld128(Bs, wc * 64 + q * 16 + (lane & 15), cbb);
#pragma unroll
            for (int m = 0; m < 4; ++m) {
#pragma unroll
                for (int q = 0; q < 4; ++q)
                    acc[m][q] = __builtin_amdgcn_mfma_f32_16x16x32_bf16(af[m], bf[q], acc[m][q], 0, 0, 0);
            }
        }
    }
#pragma unroll
    for (int m = 0; m < 4; ++m) {
#pragma unroll
        for (int q = 0; q < 4; ++q) {
            const int r0 = rowBase + wr * 64 + m * 16 + ((lane >> 4) << 2);
            const int c  = colBase + wc * 64 + q * 16 + (lane & 15);
            const float bb = bias[c];
#pragma unroll
            for (int g = 0; g < 4; ++g) Out[(size_t)(r0 + g) * DD + c] = acc[m][q][g] + bb;
        }
    }
}

// ---------- pass 1: inv column-sum of exp(sim) ----------
// grid (4,64), 512 thr. Block = (bh, j-quarter). Wave w owns j-band jg*256+w*32
// (K in regs); Q streams through LDS: 4 phases x 8 tiles (32KB), double-buffered.
// Each wave sums over ALL i -> direct invcol store. No atomics, no combine.
__global__ __launch_bounds__(512, 2) void colsum_k(
    const u16* __restrict__ qb, const u16* __restrict__ kb, float* __restrict__ invcol)
{
    alignas(16) __shared__ char smem[65536];
    const int tid = threadIdx.x;
    const int lane = tid & 63, wid = tid >> 6;
    const int il = lane & 31, hh = lane >> 5;
    const int n = blockIdx.x + 4 * blockIdx.y;
    const int L = (n & 7) * 32 + (n >> 3);   // XCD-contiguous: XCD k -> b=k
    const int jg = L & 3, bh = L >> 2;
    const int b = bh >> 3, h = bh & 7;
    const int jbase = jg * 256 + wid * 32;

    const u16* kRow = kb + (size_t)(b * NN + jbase + il) * DD + h * DH + hh * 8;
    short8 kf[4];
#pragma unroll
    for (int t = 0; t < 4; ++t) kf[t] = *(const short8*)(kRow + t * 16);

    const u16* qg0 = qb + (size_t)(b * NN) * DD + h * DH;

    auto stageQ = [&](int p, char* buf) {
#pragma unroll
        for (int r = 0; r < 4; ++r) {
            int c = r * 512 + tid;               // 0..2047 chunks
            int t = c >> 8, s = c & 255;
            int line = s >> 4, s15 = s & 15;
            int jr = p * 256 + t * 32 + line * 2 + (s15 >> 3);
            int slot8 = (s15 & 7) ^ (line & 7);
            stage_gll((const char*)(qg0 + (size_t)jr * DD) + slot8 * 16, buf + c * 16);
        }
    };

    float cp[16] = {};
    stageQ(0, smem);
    for (int p = 0; p < 4; ++p) {
        char* buf = smem + (p & 1) * 32768;
        __syncthreads();                          // stage(p) complete, reads(p-1) done
        if (p < 3) stageQ(p + 1, smem + ((p + 1) & 1) * 32768);
#pragma unroll
        for (int u = 0; u < 8; ++u) {
            short8 qf[4];
#pragma unroll
            for (int t = 0; t < 4; ++t) qf[t] = ldF2(buf + u * 4096, il, hh, t);
            f32x16 sa = {};
#pragma unroll
            for (int t = 0; t < 4; ++t)
                sa = __builtin_amdgcn_mfma_f32_32x32x16_bf16(kf[t], qf[t], sa, 0, 0, 0);
#pragma unroll
            for (int r = 0; r < 16; ++r) cp[r] += exp2f(sa[r] * EXP2C);
        }
    }
#pragma unroll
    for (int r = 0; r < 16; ++r) {
        cp[r] += __shfl_xor(cp[r], 1);
        cp[r] += __shfl_xor(cp[r], 2);
        cp[r] += __shfl_xor(cp[r], 4);
        cp[r] += __shfl_xor(cp[r], 8);
        cp[r] += __shfl_xor(cp[r], 16);
    }
    if (il == 0) {
#pragma unroll
        for (int r = 0; r < 16; ++r) {
            const int j = jbase + (r & 3) + 8 * (r >> 2) + 4 * hh;
            invcol[(size_t)bh * NN + j] = 1.0f / cp[r];
        }
    }
}

// ---------- pass 2: out^T = V^T @ P^T, P = exp(sim)*invcol ----------
// grid (4,64), 512 thr. Block = (bh, i-quarter). Wave w owns i-band ig*256+w*32
// (Q in regs); K+V stream through LDS: 8 phases x 4 jt (K 16KB + V 16KB),
// double-buffered, shared by all 8 waves. Each wave covers ALL j -> no combine.
__global__ __launch_bounds__(512, 2) void attn_k(
    const u16* __restrict__ qb, const u16* __restrict__ kb, const u16* __restrict__ vT,
    const float* __restrict__ invcol, u16* __restrict__ ob)
{
    alignas(16) __shared__ char smem[65536];
    const int tid = threadIdx.x;
    const int lane = tid & 63, wid = tid >> 6;
    const int il = lane & 31, hh = lane >> 5;
    const int n = blockIdx.x + 4 * blockIdx.y;
    const int L = (n & 7) * 32 + (n >> 3);
    const int ig = L & 3, bh = L >> 2;
    const int b = bh >> 3, h = bh & 7;
    const int ibase = ig * 256 + wid * 32;

    const u16* qRow = qb + (size_t)(b * NN + ibase + il) * DD + h * DH + hh * 8;
    short8 qf[4];
#pragma unroll
    for (int t = 0; t < 4; ++t) qf[t] = *(const short8*)(qRow + t * 16);

    const u16* kg0 = kb + (size_t)(b * NN) * DD + h * DH;
    const u16* vg0 = vT + (size_t)h * DH * 8192 + b * NN;
    const float* icbase = invcol + (size_t)bh * NN + 4 * hh;

    auto stageKV = [&](int p, char* buf) {
        const int j0 = p * 128;
#pragma unroll
        for (int r = 0; r < 4; ++r) {
            int c = r * 512 + tid;               // 0..2047; tiles: 0-3 K, 4-7 V
            int t = c >> 8, s = c & 255;
            int line = s >> 4, s15 = s & 15;
            const char* src;
            if (t < 4) {
                int jr = j0 + t * 32 + line * 2 + (s15 >> 3);
                int slot8 = (s15 & 7) ^ (line & 7);
                src = (const char*)(kg0 + (size_t)jr * DD) + slot8 * 16;
            } else {
                int s16 = s15 ^ (line & 7);
                int rr = line * 4 + (s16 >> 2);
                int slot4 = s16 & 3;
                src = (const char*)(vg0 + (size_t)rr * 8192 + j0 + (t - 4) * 32) + slot4 * 16;
            }
            stage_gll(src, buf + c * 16);
        }
    };

    f32x16 oacc[2] = {};
    float rs = 0.0f;

    stageKV(0, smem);
    for (int p = 0; p < 8; ++p) {
        char* buf = smem + (p & 1) * 32768;
        __syncthreads();                          // stage(p) complete, reads(p-1) done
        if (p < 7) stageKV(p + 1, smem + ((p + 1) & 1) * 32768);
#pragma unroll
        for (int u = 0; u < 4; ++u) {
            const int jb = (p * 4 + u) * 32;
            const char* Kt = buf + u * 4096;
            const char* Vt = buf + 16384 + u * 4096;
            short8 kf[4], vf[2][2];
#pragma unroll
            for (int t = 0; t < 4; ++t) kf[t] = ldF2(Kt, il, hh, t);
#pragma unroll
            for (int m = 0; m < 2; ++m)
#pragma unroll
                for (int tc = 0; tc < 2; ++tc) vf[m][tc] = ldF4(Vt, il, hh, m, tc);
            f32x16 sa = {};
#pragma unroll
            for (int t = 0; t < 4; ++t)
                sa = __builtin_amdgcn_mfma_f32_32x32x16_bf16(kf[t], qf[t], sa, 0, 0, 0);
            u32 pk[4][2];
#pragma unroll
            for (int s = 0; s < 4; ++s) {
                const float4 ic = *(const float4*)(icbase + jb + 8 * s);
                const float p0 = exp2f(sa[4 * s + 0] * EXP2C) * ic.x;
                const float p1 = exp2f(sa[4 * s + 1] * EXP2C) * ic.y;
                const float p2 = exp2f(sa[4 * s + 2] * EXP2C) * ic.z;
                const float p3 = exp2f(sa[4 * s + 3] * EXP2C) * ic.w;
                rs += (p0 + p1) + (p2 + p3);
                pk[s][0] = (u32)f2bf(p0) | ((u32)f2bf(p1) << 16);
                pk[s][1] = (u32)f2bf(p2) | ((u32)f2bf(p3) << 16);
            }
#pragma unroll
            for (int tc = 0; tc < 2; ++tc) {
                const u32 snd0 = hh ? pk[2 * tc][0] : pk[2 * tc + 1][0];
                const u32 snd1 = hh ? pk[2 * tc][1] : pk[2 * tc + 1][1];
                const u32 rcv0 = (u32)__shfl_xor((int)snd0, 32);
                const u32 rcv1 = (u32)__shfl_xor((int)snd1, 32);
                u32x4 pw;
                pw.x = hh ? rcv0 : pk[2 * tc][0];
                pw.y = hh ? rcv1 : pk[2 * tc][1];
                pw.z = hh ? pk[2 * tc + 1][0] : rcv0;
                pw.w = hh ? pk[2 * tc + 1][1] : rcv1;
                const short8 pf = __builtin_bit_cast(short8, pw);
#pragma unroll
                for (int m = 0; m < 2; ++m)
                    oacc[m] = __builtin_amdgcn_mfma_f32_32x32x16_bf16(vf[m][tc], pf, oacc[m], 0, 0, 0);
            }
        }
    }

    rs += __shfl_xor(rs, 32);
    const float inv = 1.0f / (rs + 1e-7f);
    u16* oRow = ob + (size_t)(b * NN + ibase + il) * DD + h * DH;
#pragma unroll
    for (int m = 0; m < 2; ++m) {
#pragma unroll
        for (int s = 0; s < 4; ++s) {
            ushort4v st;
#pragma unroll
            for (int g = 0; g < 4; ++g) st[g] = f2bf(oacc[m][4 * s + g] * inv);
            *(ushort4v*)(oRow + m * 32 + 8 * s + 4 * hh) = st;
        }
    }
}

// ---------- launcher ----------

extern "C" void kernel_launch(void* const* d_in, const int* in_sizes, int n_in,
                              void* d_out, int out_size, void* d_ws, size_t ws_size,
                              hipStream_t stream)
{
    (void)in_sizes; (void)n_in; (void)out_size; (void)ws_size;
    const float* x   = (const float*)d_in[0];
    const float* ctx = (const float*)d_in[1];
    const float* Wq  = (const float*)d_in[2];
    const float* Wk  = (const float*)d_in[3];
    const float* Wv  = (const float*)d_in[4];
    const float* Wo  = (const float*)d_in[5];
    const float* bo  = (const float*)d_in[6];
    float* out = (float*)d_out;

    char* w = (char*)d_ws;
    const size_t SZBIG = 8192ull * 512 * 2;            // 8 MiB bf16 buffer
    u16* xb  = (u16*)(w);
    u16* cb  = (u16*)(w + SZBIG);
    u16* qb  = (u16*)(w + 2 * SZBIG);
    u16* kb  = (u16*)(w + 3 * SZBIG);
    u16* vT  = (u16*)(w + 4 * SZBIG);                  // [512][8192]
    u16* wb  = (u16*)(w + 5 * SZBIG);                  // wq,wk,wv,wo contiguous
    u16* wob = wb + 3 * 262144;
    float* invcol = (float*)(w + 5 * SZBIG + 4 * 524288);
    u16* ob = xb;                                      // reuse (x dead after q GEMM)

    f2bf_all<<<9216, 256, 0, stream>>>(x, ctx, Wq, Wk, Wv, Wo, xb, cb, wb);

    gemm_qkv<<<dim3(4, 64, 3), 256, 0, stream>>>(xb, cb, wb, qb, kb, vT);

    colsum_k<<<dim3(4, 64), 512, 0, stream>>>(qb, kb, invcol);
    attn_k  <<<dim3(4, 64), 512, 0, stream>>>(qb, kb, vT, invcol, ob);

    gemm_out<<<dim3(4, 64), 256, 0, stream>>>(ob, wob, out, bo);
}